// Round 1
// baseline (2360.671 us; speedup 1.0000x reference)
//
#include <hip/hip_runtime.h>
#include <hip/hip_bf16.h>

#define K_DIM 4096
#define M_DIM 8192
#define N_DIM 16384

#define BM 128
#define BN 128
#define BK 32
#define TILES_M (M_DIM / BM)   // 64
#define TILES_N (N_DIM / BN)   // 128
#define GROUP_N 16

typedef __attribute__((ext_vector_type(8))) __bf16 bf16x8;
typedef __attribute__((ext_vector_type(4))) float f32x4;
typedef __attribute__((ext_vector_type(8))) unsigned short ushort8v;

// ---------------- pre-pass: x fp32 -> bf16 (RNE) ----------------
__global__ void cvt_x_kernel(const float* __restrict__ x,
                             unsigned short* __restrict__ xq, int n) {
  int i0 = (blockIdx.x * blockDim.x + threadIdx.x) * 8;
  int stride = gridDim.x * blockDim.x * 8;
  for (int i = i0; i < n; i += stride) {
    const float4* p = (const float4*)(x + i);
    float4 v0 = p[0];
    float4 v1 = p[1];
    float vs[8] = {v0.x, v0.y, v0.z, v0.w, v1.x, v1.y, v1.z, v1.w};
    ushort8v o;
#pragma unroll
    for (int j = 0; j < 8; ++j) {
      unsigned int u = __float_as_uint(vs[j]);
      o[j] = (unsigned short)((u + 0x7FFFu + ((u >> 16) & 1u)) >> 16);  // RNE
    }
    *(ushort8v*)(xq + i) = o;
  }
}

// ------------- pre-pass: W fp32 -> sign(W) as bf16 (exact) -------------
__global__ void quant_w_kernel(const float* __restrict__ w,
                               unsigned short* __restrict__ wq, int n) {
  int i0 = (blockIdx.x * blockDim.x + threadIdx.x) * 8;
  int stride = gridDim.x * blockDim.x * 8;
  for (int i = i0; i < n; i += stride) {
    const float4* p = (const float4*)(w + i);
    float4 v0 = p[0];
    float4 v1 = p[1];
    float vs[8] = {v0.x, v0.y, v0.z, v0.w, v1.x, v1.y, v1.z, v1.w};
    ushort8v o;
#pragma unroll
    for (int j = 0; j < 8; ++j) {
      // sign(): +1 -> 0x3F80, -1 -> 0xBF80, 0 -> 0
      o[j] = (vs[j] > 0.f) ? (unsigned short)0x3F80u
                           : ((vs[j] < 0.f) ? (unsigned short)0xBF80u
                                            : (unsigned short)0u);
    }
    *(ushort8v*)(wq + i) = o;
  }
}

// ---------------- GEMM: C[M,N] = A[M,K] * B[N,K]^T (both bf16, K-major) ----------------
__device__ __forceinline__ void gload_lds16(const unsigned short* g,
                                            unsigned short* l) {
  __builtin_amdgcn_global_load_lds(
      (const __attribute__((address_space(1))) void*)(uintptr_t)g,
      (__attribute__((address_space(3))) void*)(uintptr_t)l, 16, 0, 0);
}

__global__ __launch_bounds__(256) void gemm_bt_kernel(
    const unsigned short* __restrict__ A, const unsigned short* __restrict__ B,
    float* __restrict__ C) {
  __shared__ __align__(16) unsigned short As[BM * BK];  // 8 KB, row-major [128][32], NO pad
  __shared__ __align__(16) unsigned short Bs[BN * BK];  // 8 KB

  // block swizzle: groups of GROUP_N n-tiles sweep all m-tiles (L3 locality)
  int bid = blockIdx.x;
  int group = bid / (TILES_M * GROUP_N);
  int r = bid % (TILES_M * GROUP_N);
  int tn = group * GROUP_N + (r % GROUP_N);
  int tm = r / GROUP_N;

  const int t = threadIdx.x;
  const int lane = t & 63;
  const int wave = t >> 6;   // 0..3
  const int wr = wave >> 1;  // wave row (m), 0..1
  const int wc = wave & 1;   // wave col (n), 0..1
  const int quad = lane >> 4;
  const int l16 = lane & 15;

  const int m0 = tm * BM;
  const int n0 = tn * BN;

  // staging: chunk c = round*256 + t; row = c>>2; kcol = (c&3)*8; 16B per chunk
  const unsigned short* gA0 = A + (size_t)(m0 + (t >> 2)) * K_DIM + (t & 3) * 8;
  const unsigned short* gA1 = A + (size_t)(m0 + 64 + (t >> 2)) * K_DIM + (t & 3) * 8;
  const unsigned short* gB0 = B + (size_t)(n0 + (t >> 2)) * K_DIM + (t & 3) * 8;
  const unsigned short* gB1 = B + (size_t)(n0 + 64 + (t >> 2)) * K_DIM + (t & 3) * 8;

  // wave-uniform LDS bases (HW adds lane*16 bytes)
  unsigned short* ldsA0 = As + (size_t)(wave * 64) * 8;
  unsigned short* ldsA1 = As + (size_t)(256 + wave * 64) * 8;
  unsigned short* ldsB0 = Bs + (size_t)(wave * 64) * 8;
  unsigned short* ldsB1 = Bs + (size_t)(256 + wave * 64) * 8;

  f32x4 acc[4][4];
#pragma unroll
  for (int i = 0; i < 4; ++i)
#pragma unroll
    for (int j = 0; j < 4; ++j) acc[i][j] = (f32x4){0.f, 0.f, 0.f, 0.f};

  for (int k0 = 0; k0 < K_DIM; k0 += BK) {
    __syncthreads();  // previous iter's LDS reads done before overwrite
    gload_lds16(gA0 + k0, ldsA0);
    gload_lds16(gA1 + k0, ldsA1);
    gload_lds16(gB0 + k0, ldsB0);
    gload_lds16(gB1 + k0, ldsB1);
    __syncthreads();  // drains vmcnt (compiler emits s_waitcnt before s_barrier)

    bf16x8 af[4], bq[4];
#pragma unroll
    for (int i = 0; i < 4; ++i)
      af[i] = *(const bf16x8*)(As + (size_t)(wr * 64 + i * 16 + l16) * BK + quad * 8);
#pragma unroll
    for (int j = 0; j < 4; ++j)
      bq[j] = *(const bf16x8*)(Bs + (size_t)(wc * 64 + j * 16 + l16) * BK + quad * 8);

#pragma unroll
    for (int i = 0; i < 4; ++i)
#pragma unroll
      for (int j = 0; j < 4; ++j)
        acc[i][j] = __builtin_amdgcn_mfma_f32_16x16x32_bf16(af[i], bq[j],
                                                            acc[i][j], 0, 0, 0);
  }

  // epilogue: C[m0 + wr*64 + i*16 + quad*4 + r][n0 + wc*64 + j*16 + l16]
  float* Cw = C + (size_t)(m0 + wr * 64 + quad * 4) * N_DIM + n0 + wc * 64 + l16;
#pragma unroll
  for (int i = 0; i < 4; ++i)
#pragma unroll
    for (int j = 0; j < 4; ++j)
#pragma unroll
      for (int rr = 0; rr < 4; ++rr)
        Cw[(size_t)(i * 16 + rr) * N_DIM + j * 16] = acc[i][j][rr];
}

extern "C" void kernel_launch(void* const* d_in, const int* in_sizes, int n_in,
                              void* d_out, int out_size, void* d_ws,
                              size_t ws_size, hipStream_t stream) {
  const float* x = (const float*)d_in[0];   // [2*4096, 4096]
  const float* w = (const float*)d_in[1];   // [16384, 4096]
  float* out = (float*)d_out;               // [2*4096, 16384]

  unsigned short* xq = (unsigned short*)d_ws;                  // 64 MiB
  unsigned short* wq = xq + (size_t)M_DIM * K_DIM;             // 128 MiB

  {
    int n = M_DIM * K_DIM;
    int blocks = n / (256 * 8);
    cvt_x_kernel<<<blocks, 256, 0, stream>>>(x, xq, n);
  }
  {
    int n = N_DIM * K_DIM;
    int blocks = n / (256 * 8);
    quant_w_kernel<<<blocks, 256, 0, stream>>>(w, wq, n);
  }
  gemm_bt_kernel<<<TILES_M * TILES_N, 256, 0, stream>>>(xq, wq, out);
}